// Round 6
// baseline (588.630 us; speedup 1.0000x reference)
//
#include <hip/hip_runtime.h>
#include <cstddef>

#define WC_CONST 0.2357022603955158f   // sqrt(2/(9*4))
#define WL_CONST 0.5773502691896258f   // sqrt(1/3)

// ---------------- concat projection weights into [384][1152] ----------------
__global__ __launch_bounds__(256) void concat_w_kernel(
    const float* __restrict__ Wq, const float* __restrict__ Wk, const float* __restrict__ Wv,
    const float* __restrict__ Wqp, const float* __restrict__ Wkp, const float* __restrict__ Wvp,
    float* __restrict__ Wcat) {
  int idx = blockIdx.x * 256 + threadIdx.x;
  if (idx >= 384 * 1152) return;
  int k = idx / 1152, c = idx % 1152;
  float v;
  if (c < 192)       v = Wq [k*192 + c];
  else if (c < 384)  v = Wk [k*192 + (c-192)];
  else if (c < 576)  v = Wv [k*192 + (c-384)];
  else if (c < 720)  v = Wqp[k*144 + (c-576)];
  else if (c < 864)  v = Wkp[k*144 + (c-720)];
  else               v = Wvp[k*288 + (c-864)];
  Wcat[idx] = v;
}

// ---------------- generic fp32 tiled GEMM, 64x64 tile, split-K ----------------
__global__ __launch_bounds__(256) void gemm64_kernel(
    const float* __restrict__ Amat, const float* __restrict__ Bmat, float* __restrict__ Cp,
    int M, int N, int K, int ksl) {
  __shared__ float As[16][68];
  __shared__ float Bs[16][68];
  int t = threadIdx.x;
  int bn = blockIdx.x, bm = blockIdx.y, bz = blockIdx.z;
  int k0 = bz * ksl;
  int tr = t >> 4, tc = t & 15;
  int lm = t >> 2, lk4 = (t & 3) << 2;
  int lkb = t >> 4, lnq = (t & 15) << 2;
  const float* Ab = Amat + (size_t)(bm*64 + lm) * K;
  const float* Bb = Bmat + bn*64 + lnq;
  float acc[4][4];
  #pragma unroll
  for (int a2 = 0; a2 < 4; a2++)
    #pragma unroll
    for (int b2 = 0; b2 < 4; b2++) acc[a2][b2] = 0.f;

  for (int k = k0; k < k0 + ksl; k += 16) {
    float4 av = *(const float4*)(Ab + k + lk4);
    float4 bv = *(const float4*)(Bb + (size_t)(k + lkb) * N);
    As[lk4+0][lm] = av.x; As[lk4+1][lm] = av.y; As[lk4+2][lm] = av.z; As[lk4+3][lm] = av.w;
    *(float4*)&Bs[lkb][lnq] = bv;
    __syncthreads();
    #pragma unroll
    for (int kk = 0; kk < 16; kk++) {
      float4 a4 = *(const float4*)&As[kk][tr << 2];
      float4 b4 = *(const float4*)&Bs[kk][tc << 2];
      float ar[4] = {a4.x, a4.y, a4.z, a4.w};
      float br[4] = {b4.x, b4.y, b4.z, b4.w};
      #pragma unroll
      for (int a2 = 0; a2 < 4; a2++)
        #pragma unroll
        for (int b2 = 0; b2 < 4; b2++) acc[a2][b2] += ar[a2] * br[b2];
    }
    __syncthreads();
  }
  float* Cb = Cp + (size_t)bz * M * N + (size_t)(bm*64 + (tr << 2)) * N + bn*64 + (tc << 2);
  #pragma unroll
  for (int r = 0; r < 4; r++) {
    float4 o = {acc[r][0], acc[r][1], acc[r][2], acc[r][3]};
    *(float4*)(Cb + (size_t)r * N) = o;
  }
}

// ---------------- split-K reduce ----------------
__global__ __launch_bounds__(256) void reduce_kernel(
    const float* __restrict__ Cp, float* __restrict__ out, const float* __restrict__ bias,
    int relu, int MN, int N, int sk) {
  int idx = blockIdx.x * 256 + threadIdx.x;
  if (idx >= MN) return;
  float s = 0.f;
  for (int z = 0; z < sk; z++) s += Cp[(size_t)z * MN + idx];
  if (bias) s += bias[idx % N];
  if (relu) s = fmaxf(s, 0.f);
  out[idx] = s;
}

// ---------------- 32x32-tile GEMM, fused bias/relu ----------------
__global__ __launch_bounds__(256) void gemm32_kernel(
    const float* __restrict__ Amat, const float* __restrict__ Bmat,
    const float* __restrict__ bias,
    float* __restrict__ C, int M, int N, int K, int relu) {
  __shared__ float As[16][34];
  __shared__ float Bs[16][34];
  int t = threadIdx.x;
  int bn = blockIdx.x, bm = blockIdx.y;
  int tr = t >> 4, tc = t & 15;
  int lm = t >> 3, lk2 = (t & 7) << 1;
  int lkb = t >> 4, ln2 = (t & 15) << 1;
  const float* Ab = Amat + (size_t)(bm*32 + lm) * K;
  const float* Bb = Bmat + bn*32 + ln2;
  float a00=0.f, a01=0.f, a10=0.f, a11=0.f;
  for (int k = 0; k < K; k += 16) {
    float2 av = *(const float2*)(Ab + k + lk2);
    float2 bv = *(const float2*)(Bb + (size_t)(k + lkb) * N);
    As[lk2][lm] = av.x; As[lk2+1][lm] = av.y;
    *(float2*)&Bs[lkb][ln2] = bv;
    __syncthreads();
    #pragma unroll
    for (int kk = 0; kk < 16; kk++) {
      float2 a2 = *(const float2*)&As[kk][tr << 1];
      float2 b2 = *(const float2*)&Bs[kk][tc << 1];
      a00 += a2.x*b2.x; a01 += a2.x*b2.y; a10 += a2.y*b2.x; a11 += a2.y*b2.y;
    }
    __syncthreads();
  }
  int r0 = bm*32 + (tr << 1), c0 = bn*32 + (tc << 1);
  float bb0 = bias ? bias[c0] : 0.f, bb1 = bias ? bias[c0+1] : 0.f;
  float o00 = a00 + bb0, o01 = a01 + bb1, o10 = a10 + bb0, o11 = a11 + bb1;
  if (relu) { o00=fmaxf(o00,0.f); o01=fmaxf(o01,0.f); o10=fmaxf(o10,0.f); o11=fmaxf(o11,0.f); }
  float2 w0 = {o00, o01}, w1 = {o10, o11};
  *(float2*)(C + (size_t)r0*N + c0) = w0;
  *(float2*)(C + (size_t)(r0+1)*N + c0) = w1;
}

// ---------------- frames ----------------
__global__ __launch_bounds__(64) void frames_kernel(
    const float* __restrict__ proj, const float* __restrict__ quat, const float* __restrict__ trsl,
    float* __restrict__ rotb, float* __restrict__ qpg, float* __restrict__ kpg,
    float* __restrict__ vpg) {
  int i = blockIdx.x, t = threadIdx.x;
  float q0 = quat[i*3+0], q1 = quat[i*3+1], q2 = quat[i*3+2];
  float inv = rsqrtf(1.f + q0*q0 + q1*q1 + q2*q2);
  float w = inv, x = q0*inv, y = q1*inv, z = q2*inv;
  float R00 = 1.f - 2.f*(y*y + z*z), R01 = 2.f*(x*y - w*z), R02 = 2.f*(x*z + w*y);
  float R10 = 2.f*(x*y + w*z), R11 = 1.f - 2.f*(x*x + z*z), R12 = 2.f*(y*z - w*x);
  float R20 = 2.f*(x*z - w*y), R21 = 2.f*(y*z + w*x), R22 = 1.f - 2.f*(x*x + y*y);
  float t0 = trsl[i*3+0], t1 = trsl[i*3+1], t2 = trsl[i*3+2];
  if (t == 0) {
    float* rb = rotb + i*9;
    rb[0]=R00; rb[1]=R01; rb[2]=R02; rb[3]=R10; rb[4]=R11; rb[5]=R12; rb[6]=R20; rb[7]=R21; rb[8]=R22;
  }
  for (int pt = t; pt < 192; pt += 64) {
    const float* src; float* dst;
    if (pt < 48)      { src = proj + i*1152 + 576 + pt*3;        dst = qpg + i*144 + pt*3; }
    else if (pt < 96) { src = proj + i*1152 + 720 + (pt-48)*3;   dst = kpg + i*144 + (pt-48)*3; }
    else              { src = proj + i*1152 + 864 + (pt-96)*3;   dst = vpg + i*288 + (pt-96)*3; }
    float p0 = src[0], p1 = src[1], p2 = src[2];
    dst[0] = R00*p0 + R01*p1 + R02*p2 + t0;
    dst[1] = R10*p0 + R11*p1 + R12*p2 + t1;
    dst[2] = R20*p0 + R21*p1 + R22*p2 + t2;
  }
}

// ---------------- logit (qk/4 - coef*d2) ----------------
__device__ __forceinline__ float lt1_val(
    const float* __restrict__ proj, const float* __restrict__ kpg,
    const float* qs_, const float* qps_, float coef, int jg, int h) {
  const float4* kr = (const float4*)(proj + (size_t)jg*1152 + 192 + h*16);
  const float4* qr = (const float4*)(qs_ + h*16);
  float qk = 0.f;
  #pragma unroll
  for (int m = 0; m < 4; m++) {
    float4 kv = kr[m], qv = qr[m];
    qk += qv.x*kv.x + qv.y*kv.y + qv.z*kv.z + qv.w*kv.w;
  }
  const float4* kpr = (const float4*)(kpg + (size_t)jg*144 + h*12);
  const float4* qpr = (const float4*)(qps_ + h*12);
  float d2 = 0.f;
  #pragma unroll
  for (int m = 0; m < 3; m++) {
    float4 kv = kpr[m], qv = qpr[m];
    float dx = qv.x-kv.x, dy = qv.y-kv.y, dz = qv.z-kv.z, dw = qv.w-kv.w;
    d2 += dx*dx + dy*dy + dz*dz + dw*dw;
  }
  return qk*0.25f - coef*d2;
}

// ---------------- fused attention, register-streaming, no pfea staging -------
// 768 thr = 12 waves. Wave w owns rows j = w, w+12, ...; lane owns cols 4L..4L+3.
// Per row: one coalesced float4 pfea load -> b-partial (48 FMA) -> 64-lane
// butterfly -> exp -> op/ov/ovp accumulation, all in registers. Barriers only
// at start/end.
__global__ __launch_bounds__(768) void attn4_kernel(
    const float* __restrict__ proj, const float* __restrict__ qpg,
    const float* __restrict__ kpg, const float* __restrict__ vpg,
    const float* __restrict__ pfea, const float* __restrict__ Wb,
    const float* __restrict__ rotb, const float* __restrict__ trsl,
    const float* __restrict__ scale, float* __restrict__ shid) {
  __shared__ float Lb[512][12];                 // 24576 B
  __shared__ __align__(16) float4 opred[12][2][64];  // 24576 B (aliased by fred)
  __shared__ __align__(16) float qs[12][16];
  __shared__ __align__(16) float qps[12][12];
  __shared__ float coefs[12], sh_inv[12], rot_s[9];
  __shared__ float sred[12][12];
  __shared__ float ovpg_l[12][24];

  int i = blockIdx.x, t = threadIdx.x;
  int w = t >> 6, lane = t & 63;

  for (int idx = t; idx < 192; idx += 768) qs[idx >> 4][idx & 15] = proj[i*1152 + idx];
  for (int idx = t; idx < 144; idx += 768) qps[idx / 12][idx % 12] = qpg[i*144 + idx];
  if (t < 12) coefs[t] = WC_CONST * 0.5f * log1pf(__expf(scale[t]));
  if (t < 9)  rot_s[t] = rotb[i*9 + t];
  __syncthreads();

  // Lb fill: 512*12 / 768 = 8 per thread
  #pragma unroll
  for (int r = 0; r < 8; r++) {
    int idx = t + r * 768;
    int j = idx / 12, h = idx - j * 12;
    Lb[j][h] = lt1_val(proj, kpg, &qs[0][0], &qps[0][0], coefs[h], j, h);
  }
  // Wb rows for this lane's 4 columns (L2-resident, once)
  float wbr[48];
  #pragma unroll
  for (int c = 0; c < 4; c++)
    #pragma unroll
    for (int h = 0; h < 12; h++)
      wbr[c * 12 + h] = Wb[(size_t)(lane * 4 + c) * 12 + h];
  __syncthreads();

  // accumulators
  float4 opacc[12];
  #pragma unroll
  for (int h = 0; h < 12; h++) { opacc[h].x=0.f; opacc[h].y=0.f; opacc[h].z=0.f; opacc[h].w=0.f; }
  float accv[3] = {0.f, 0.f, 0.f};
  float accvp[5] = {0.f, 0.f, 0.f, 0.f, 0.f};
  float sacc[12];
  #pragma unroll
  for (int h = 0; h < 12; h++) sacc[h] = 0.f;

  int hv0 = lane >> 4, hv1 = 4 + (lane >> 4), hv2 = 8 + (lane >> 4);
  int hp0 = lane / 24, hp1 = (lane + 64) / 24, hp2 = (lane + 128) / 24,
      hp3 = (lane + 192) / 24, hp4 = (lane + 256) / 24;

  const float* pf = pfea + (size_t)i * 131072 + (lane << 2);
  int nrows = (w < 8) ? 43 : 42;   // 512 = 8*43 + 4*42

  // 2-deep pfea prefetch
  float4 pv0 = *(const float4*)(pf + (size_t)w * 256);
  float4 pv1 = (nrows > 1) ? *(const float4*)(pf + (size_t)(w + 12) * 256) : pv0;

  for (int r = 0; r < nrows; r++) {
    int j = w + 12 * r;
    float4 pv = pv0;
    pv0 = pv1;
    int jn = w + 12 * (r + 2); if (jn > 511) jn = 511;
    pv1 = *(const float4*)(pf + (size_t)jn * 256);

    // issue v / vp loads early (consumed at end of body)
    const float* vrow  = proj + (size_t)j * 1152 + 384 + lane;
    const float* vprow = vpg  + (size_t)j * 288 + lane;
    float vv0 = vrow[0],  vv1 = vrow[64],  vv2 = vrow[128];
    float vp0 = vprow[0], vp1 = vprow[64], vp2 = vprow[128], vp3 = vprow[192];
    float vp4 = (lane < 32) ? vprow[256] : 0.f;

    // b partials over this lane's 4 columns
    float bp[12];
    #pragma unroll
    for (int h = 0; h < 12; h++)
      bp[h] = pv.x*wbr[h] + pv.y*wbr[12+h] + pv.z*wbr[24+h] + pv.w*wbr[36+h];
    // 64-lane butterfly reduce (12 values)
    #pragma unroll
    for (int off = 32; off >= 1; off >>= 1) {
      #pragma unroll
      for (int h = 0; h < 12; h++) bp[h] += __shfl_xor(bp[h], off);
    }
    // weights
    const float4* lbp = (const float4*)&Lb[j][0];
    float4 lb0 = lbp[0], lb1 = lbp[1], lb2 = lbp[2];
    float wv[12];
    wv[0]  = __expf(WL_CONST * (lb0.x + bp[0]));
    wv[1]  = __expf(WL_CONST * (lb0.y + bp[1]));
    wv[2]  = __expf(WL_CONST * (lb0.z + bp[2]));
    wv[3]  = __expf(WL_CONST * (lb0.w + bp[3]));
    wv[4]  = __expf(WL_CONST * (lb1.x + bp[4]));
    wv[5]  = __expf(WL_CONST * (lb1.y + bp[5]));
    wv[6]  = __expf(WL_CONST * (lb1.z + bp[6]));
    wv[7]  = __expf(WL_CONST * (lb1.w + bp[7]));
    wv[8]  = __expf(WL_CONST * (lb2.x + bp[8]));
    wv[9]  = __expf(WL_CONST * (lb2.y + bp[9]));
    wv[10] = __expf(WL_CONST * (lb2.z + bp[10]));
    wv[11] = __expf(WL_CONST * (lb2.w + bp[11]));
    #pragma unroll
    for (int h = 0; h < 12; h++) sacc[h] += wv[h];
    // op accumulation
    #pragma unroll
    for (int h = 0; h < 12; h++) {
      opacc[h].x += wv[h] * pv.x; opacc[h].y += wv[h] * pv.y;
      opacc[h].z += wv[h] * pv.z; opacc[h].w += wv[h] * pv.w;
    }
    // ov / ovp_g
    accv[0] += wv[hv0] * vv0; accv[1] += wv[hv1] * vv1; accv[2] += wv[hv2] * vv2;
    accvp[0] += wv[hp0] * vp0; accvp[1] += wv[hp1] * vp1;
    accvp[2] += wv[hp2] * vp2; accvp[3] += wv[hp3] * vp3;
    if (lane < 32) accvp[4] += wv[hp4] * vp4;
  }
  __syncthreads();

  // ---- s reduce ----
  if (lane == 0) {
    #pragma unroll
    for (int h = 0; h < 12; h++) sred[w][h] = sacc[h];
  }
  __syncthreads();
  if (t < 12) {
    float s = 0.f;
    #pragma unroll
    for (int w2 = 0; w2 < 12; w2++) s += sred[w2][t];
    sh_inv[t] = 1.0f / s;
  }
  __syncthreads();

  // ---- op reduce: 6 rounds of 2 heads ----
  #pragma unroll
  for (int g = 0; g < 6; g++) {
    opred[w][0][lane] = opacc[2*g + 0];
    opred[w][1][lane] = opacc[2*g + 1];
    __syncthreads();
    if (t < 128) {
      int hh = t >> 6, ll = t & 63;
      float4 s = {0.f, 0.f, 0.f, 0.f};
      #pragma unroll
      for (int w2 = 0; w2 < 12; w2++) {
        float4 v = opred[w2][hh][ll];
        s.x += v.x; s.y += v.y; s.z += v.z; s.w += v.w;
      }
      int h = 2*g + hh;
      float isv = sh_inv[h];
      float4 o = {s.x*isv, s.y*isv, s.z*isv, s.w*isv};
      *(float4*)(shid + (size_t)i * 3648 + h * 304 + (ll << 2)) = o;
    }
    __syncthreads();
  }

  // ---- ov reduce ----
  float* fred = (float*)&opred[0][0][0];   // 6144 floats available
  fred[w * 192 + lane]       = accv[0];
  fred[w * 192 + 64 + lane]  = accv[1];
  fred[w * 192 + 128 + lane] = accv[2];
  __syncthreads();
  if (t < 192) {
    int h = t >> 4;
    float s = 0.f;
    #pragma unroll
    for (int w2 = 0; w2 < 12; w2++) s += fred[w2 * 192 + t];
    shid[(size_t)i * 3648 + h * 304 + 256 + (t & 15)] = s * sh_inv[h];
  }
  __syncthreads();

  // ---- ovp reduce ----
  #pragma unroll
  for (int k = 0; k < 4; k++) fred[w * 288 + 64 * k + lane] = accvp[k];
  if (lane < 32) fred[w * 288 + 256 + lane] = accvp[4];
  __syncthreads();
  if (t < 288) {
    int h = t / 24;
    float s = 0.f;
    #pragma unroll
    for (int w2 = 0; w2 < 12; w2++) s += fred[w2 * 288 + t];
    ovpg_l[h][t - h * 24] = s * sh_inv[h];
  }
  __syncthreads();

  // ---- ovp = rot^T (ovp_g - t), norms ----
  if (t < 96) {
    int h = t >> 3, vv = t & 7;
    float x = ovpg_l[h][vv*3+0] - trsl[i*3+0];
    float y = ovpg_l[h][vv*3+1] - trsl[i*3+1];
    float z = ovpg_l[h][vv*3+2] - trsl[i*3+2];
    float o0 = rot_s[0]*x + rot_s[3]*y + rot_s[6]*z;
    float o1 = rot_s[1]*x + rot_s[4]*y + rot_s[7]*z;
    float o2 = rot_s[2]*x + rot_s[5]*y + rot_s[8]*z;
    float* so = shid + (size_t)i*3648 + h*304 + 272 + vv*3;
    so[0] = o0; so[1] = o1; so[2] = o2;
    shid[(size_t)i*3648 + h*304 + 296 + vv] = sqrtf(o0*o0 + o1*o1 + o2*o2);
  }
}

// ---------------- LayerNorm over 384 ----------------
__global__ __launch_bounds__(384) void ln384_kernel(
    const float* __restrict__ resid, const float* __restrict__ C, const float* __restrict__ bias,
    const float* __restrict__ g, const float* __restrict__ be, float* __restrict__ out) {
  int i = blockIdx.x, t = threadIdx.x;
  __shared__ float red[6];
  float x = resid[(size_t)i*384 + t] + C[(size_t)i*384 + t] + bias[t];
  float s = x;
  #pragma unroll
  for (int off = 32; off >= 1; off >>= 1) s += __shfl_xor(s, off);
  if ((t & 63) == 0) red[t >> 6] = s;
  __syncthreads();
  float m = (red[0]+red[1]+red[2]+red[3]+red[4]+red[5]) * (1.f/384.f);
  __syncthreads();
  float d = x - m;
  float v = d * d;
  #pragma unroll
  for (int off = 32; off >= 1; off >>= 1) v += __shfl_xor(v, off);
  if ((t & 63) == 0) red[t >> 6] = v;
  __syncthreads();
  float var = (red[0]+red[1]+red[2]+red[3]+red[4]+red[5]) * (1.f/384.f);
  out[(size_t)i*384 + t] = d * rsqrtf(var + 1e-5f) * g[t] + be[t];
}

// ---------------- launcher ----------------
extern "C" void kernel_launch(void* const* d_in, const int* in_sizes, int n_in,
                              void* d_out, int out_size, void* d_ws, size_t ws_size,
                              hipStream_t stream) {
  const float* sfea = (const float*)d_in[0];
  const float* pfea = (const float*)d_in[1];
  const float* quat = (const float*)d_in[2];
  const float* trsl = (const float*)d_in[3];
  const float* Wq   = (const float*)d_in[4];
  const float* Wk   = (const float*)d_in[5];
  const float* Wv   = (const float*)d_in[6];
  const float* Wqp  = (const float*)d_in[7];
  const float* Wkp  = (const float*)d_in[8];
  const float* Wvp  = (const float*)d_in[9];
  const float* Wb   = (const float*)d_in[10];
  const float* scale= (const float*)d_in[11];
  const float* Wsm  = (const float*)d_in[12];
  const float* bs   = (const float*)d_in[13];
  const float* W1   = (const float*)d_in[14];
  const float* b1   = (const float*)d_in[15];
  const float* W2   = (const float*)d_in[16];
  const float* b2   = (const float*)d_in[17];
  const float* W3   = (const float*)d_in[18];
  const float* b3   = (const float*)d_in[19];
  const float* g1   = (const float*)d_in[20];
  const float* be1  = (const float*)d_in[21];
  const float* g2   = (const float*)d_in[22];
  const float* be2  = (const float*)d_in[23];
  float* out = (float*)d_out;
  float* wsf = (float*)d_ws;

  float* Wcat = wsf;                     // 442368
  float* proj = Wcat + 442368;           // 589824
  float* rotb = proj + 589824;           // 4608
  float* qpg  = rotb + 4608;             // 73728
  float* kpg  = qpg + 73728;             // 73728
  float* vpg  = kpg + 73728;             // 147456
  float* shid = vpg + 147456;            // 1867776
  float* cpart= shid + 1867776;          // 1179648
  float* C1   = cpart + 1179648;         // 196608
  float* s1   = C1 + 196608;             // 196608
  float* h1   = s1 + 196608;             // 196608
  float* h2   = h1 + 196608;             // 196608
  float* C3   = h2 + 196608;             // 196608

  concat_w_kernel<<<1728, 256, 0, stream>>>(Wq, Wk, Wv, Wqp, Wkp, Wvp, Wcat);
  gemm64_kernel<<<dim3(18, 8, 1), 256, 0, stream>>>(sfea, Wcat, proj, 512, 1152, 384, 384);
  frames_kernel<<<512, 64, 0, stream>>>(proj, quat, trsl, rotb, qpg, kpg, vpg);
  attn4_kernel<<<512, 768, 0, stream>>>(proj, qpg, kpg, vpg, pfea, Wb, rotb, trsl, scale, shid);

  gemm64_kernel<<<dim3(6, 8, 6), 256, 0, stream>>>(shid, Wsm, cpart, 512, 384, 3648, 608);
  reduce_kernel<<<768, 256, 0, stream>>>(cpart, C1, nullptr, 0, 196608, 384, 6);
  ln384_kernel<<<512, 384, 0, stream>>>(sfea, C1, bs, g1, be1, s1);

  gemm32_kernel<<<dim3(12, 16), 256, 0, stream>>>(s1, W1, b1, h1, 512, 384, 384, 1);
  gemm32_kernel<<<dim3(12, 16), 256, 0, stream>>>(h1, W2, b2, h2, 512, 384, 384, 1);
  gemm32_kernel<<<dim3(12, 16), 256, 0, stream>>>(h2, W3, nullptr, C3, 512, 384, 384, 0);
  ln384_kernel<<<512, 384, 0, stream>>>(s1, C3, b3, g2, be2, out);
}

// Round 7
// 332.312 us; speedup vs baseline: 1.7713x; 1.7713x over previous
//
#include <hip/hip_runtime.h>
#include <cstddef>

typedef __attribute__((ext_vector_type(8))) short short8;
typedef __attribute__((ext_vector_type(4))) float f32x4;

#define WC_CONST 0.2357022603955158f   // sqrt(2/(9*4))
#define WL_CONST 0.5773502691896258f   // sqrt(1/3)

__device__ __forceinline__ unsigned short rne_bf16(float f) {
  unsigned int u = __float_as_uint(f);
  u += 0x7fffu + ((u >> 16) & 1u);
  return (unsigned short)(u >> 16);
}

// ---------------- concat projection weights into [384][1152] ----------------
__global__ __launch_bounds__(256) void concat_w_kernel(
    const float* __restrict__ Wq, const float* __restrict__ Wk, const float* __restrict__ Wv,
    const float* __restrict__ Wqp, const float* __restrict__ Wkp, const float* __restrict__ Wvp,
    float* __restrict__ Wcat) {
  int idx = blockIdx.x * 256 + threadIdx.x;
  if (idx >= 384 * 1152) return;
  int k = idx / 1152, c = idx % 1152;
  float v;
  if (c < 192)       v = Wq [k*192 + c];
  else if (c < 384)  v = Wk [k*192 + (c-192)];
  else if (c < 576)  v = Wv [k*192 + (c-384)];
  else if (c < 720)  v = Wqp[k*144 + (c-576)];
  else if (c < 864)  v = Wkp[k*144 + (c-720)];
  else               v = Wvp[k*288 + (c-864)];
  Wcat[idx] = v;
}

// ---------------- generic fp32 tiled GEMM, 64x64 tile, split-K ----------------
__global__ __launch_bounds__(256) void gemm64_kernel(
    const float* __restrict__ Amat, const float* __restrict__ Bmat, float* __restrict__ Cp,
    int M, int N, int K, int ksl) {
  __shared__ float As[16][68];
  __shared__ float Bs[16][68];
  int t = threadIdx.x;
  int bn = blockIdx.x, bm = blockIdx.y, bz = blockIdx.z;
  int k0 = bz * ksl;
  int tr = t >> 4, tc = t & 15;
  int lm = t >> 2, lk4 = (t & 3) << 2;
  int lkb = t >> 4, lnq = (t & 15) << 2;
  const float* Ab = Amat + (size_t)(bm*64 + lm) * K;
  const float* Bb = Bmat + bn*64 + lnq;
  float acc[4][4];
  #pragma unroll
  for (int a2 = 0; a2 < 4; a2++)
    #pragma unroll
    for (int b2 = 0; b2 < 4; b2++) acc[a2][b2] = 0.f;

  for (int k = k0; k < k0 + ksl; k += 16) {
    float4 av = *(const float4*)(Ab + k + lk4);
    float4 bv = *(const float4*)(Bb + (size_t)(k + lkb) * N);
    As[lk4+0][lm] = av.x; As[lk4+1][lm] = av.y; As[lk4+2][lm] = av.z; As[lk4+3][lm] = av.w;
    *(float4*)&Bs[lkb][lnq] = bv;
    __syncthreads();
    #pragma unroll
    for (int kk = 0; kk < 16; kk++) {
      float4 a4 = *(const float4*)&As[kk][tr << 2];
      float4 b4 = *(const float4*)&Bs[kk][tc << 2];
      float ar[4] = {a4.x, a4.y, a4.z, a4.w};
      float br[4] = {b4.x, b4.y, b4.z, b4.w};
      #pragma unroll
      for (int a2 = 0; a2 < 4; a2++)
        #pragma unroll
        for (int b2 = 0; b2 < 4; b2++) acc[a2][b2] += ar[a2] * br[b2];
    }
    __syncthreads();
  }
  float* Cb = Cp + (size_t)bz * M * N + (size_t)(bm*64 + (tr << 2)) * N + bn*64 + (tc << 2);
  #pragma unroll
  for (int r = 0; r < 4; r++) {
    float4 o = {acc[r][0], acc[r][1], acc[r][2], acc[r][3]};
    *(float4*)(Cb + (size_t)r * N) = o;
  }
}

// ---------------- split-K reduce ----------------
__global__ __launch_bounds__(256) void reduce_kernel(
    const float* __restrict__ Cp, float* __restrict__ out, const float* __restrict__ bias,
    int relu, int MN, int N, int sk) {
  int idx = blockIdx.x * 256 + threadIdx.x;
  if (idx >= MN) return;
  float s = 0.f;
  for (int z = 0; z < sk; z++) s += Cp[(size_t)z * MN + idx];
  if (bias) s += bias[idx % N];
  if (relu) s = fmaxf(s, 0.f);
  out[idx] = s;
}

// ---------------- 32x32-tile GEMM, fused bias/relu ----------------
__global__ __launch_bounds__(256) void gemm32_kernel(
    const float* __restrict__ Amat, const float* __restrict__ Bmat,
    const float* __restrict__ bias,
    float* __restrict__ C, int M, int N, int K, int relu) {
  __shared__ float As[16][34];
  __shared__ float Bs[16][34];
  int t = threadIdx.x;
  int bn = blockIdx.x, bm = blockIdx.y;
  int tr = t >> 4, tc = t & 15;
  int lm = t >> 3, lk2 = (t & 7) << 1;
  int lkb = t >> 4, ln2 = (t & 15) << 1;
  const float* Ab = Amat + (size_t)(bm*32 + lm) * K;
  const float* Bb = Bmat + bn*32 + ln2;
  float a00=0.f, a01=0.f, a10=0.f, a11=0.f;
  for (int k = 0; k < K; k += 16) {
    float2 av = *(const float2*)(Ab + k + lk2);
    float2 bv = *(const float2*)(Bb + (size_t)(k + lkb) * N);
    As[lk2][lm] = av.x; As[lk2+1][lm] = av.y;
    *(float2*)&Bs[lkb][ln2] = bv;
    __syncthreads();
    #pragma unroll
    for (int kk = 0; kk < 16; kk++) {
      float2 a2 = *(const float2*)&As[kk][tr << 1];
      float2 b2 = *(const float2*)&Bs[kk][tc << 1];
      a00 += a2.x*b2.x; a01 += a2.x*b2.y; a10 += a2.y*b2.x; a11 += a2.y*b2.y;
    }
    __syncthreads();
  }
  int r0 = bm*32 + (tr << 1), c0 = bn*32 + (tc << 1);
  float bb0 = bias ? bias[c0] : 0.f, bb1 = bias ? bias[c0+1] : 0.f;
  float o00 = a00 + bb0, o01 = a01 + bb1, o10 = a10 + bb0, o11 = a11 + bb1;
  if (relu) { o00=fmaxf(o00,0.f); o01=fmaxf(o01,0.f); o10=fmaxf(o10,0.f); o11=fmaxf(o11,0.f); }
  float2 w0 = {o00, o01}, w1 = {o10, o11};
  *(float2*)(C + (size_t)r0*N + c0) = w0;
  *(float2*)(C + (size_t)(r0+1)*N + c0) = w1;
}

// ---------------- frames ----------------
__global__ __launch_bounds__(64) void frames_kernel(
    const float* __restrict__ proj, const float* __restrict__ quat, const float* __restrict__ trsl,
    float* __restrict__ rotb, float* __restrict__ qpg, float* __restrict__ kpg,
    float* __restrict__ vpg) {
  int i = blockIdx.x, t = threadIdx.x;
  float q0 = quat[i*3+0], q1 = quat[i*3+1], q2 = quat[i*3+2];
  float inv = rsqrtf(1.f + q0*q0 + q1*q1 + q2*q2);
  float w = inv, x = q0*inv, y = q1*inv, z = q2*inv;
  float R00 = 1.f - 2.f*(y*y + z*z), R01 = 2.f*(x*y - w*z), R02 = 2.f*(x*z + w*y);
  float R10 = 2.f*(x*y + w*z), R11 = 1.f - 2.f*(x*x + z*z), R12 = 2.f*(y*z - w*x);
  float R20 = 2.f*(x*z - w*y), R21 = 2.f*(y*z + w*x), R22 = 1.f - 2.f*(x*x + y*y);
  float t0 = trsl[i*3+0], t1 = trsl[i*3+1], t2 = trsl[i*3+2];
  if (t == 0) {
    float* rb = rotb + i*9;
    rb[0]=R00; rb[1]=R01; rb[2]=R02; rb[3]=R10; rb[4]=R11; rb[5]=R12; rb[6]=R20; rb[7]=R21; rb[8]=R22;
  }
  for (int pt = t; pt < 192; pt += 64) {
    const float* src; float* dst;
    if (pt < 48)      { src = proj + i*1152 + 576 + pt*3;        dst = qpg + i*144 + pt*3; }
    else if (pt < 96) { src = proj + i*1152 + 720 + (pt-48)*3;   dst = kpg + i*144 + (pt-48)*3; }
    else              { src = proj + i*1152 + 864 + (pt-96)*3;   dst = vpg + i*288 + (pt-96)*3; }
    float p0 = src[0], p1 = src[1], p2 = src[2];
    dst[0] = R00*p0 + R01*p1 + R02*p2 + t0;
    dst[1] = R10*p0 + R11*p1 + R12*p2 + t1;
    dst[2] = R20*p0 + R21*p1 + R22*p2 + t2;
  }
}

// ---------------- b = pfea @ Wb via bf16 MFMA (round-1 proven) --------------
__global__ __launch_bounds__(256) void bgemm_kernel(
    const float* __restrict__ pfea, const float* __restrict__ Wb, float* __restrict__ bmat) {
  __shared__ short wbf[8][64][8];
  int t = threadIdx.x;
  for (int s = t; s < 512; s += 256) {
    int ks = s >> 6, l = s & 63;
    int col = l & 15, kb = ks * 32 + ((l >> 4) << 3);
    #pragma unroll
    for (int j = 0; j < 8; j++)
      wbf[ks][l][j] = (col < 12) ? (short)rne_bf16(Wb[(kb + j) * 12 + col]) : (short)0;
  }
  __syncthreads();
  int wv = t >> 6, lane = t & 63;
  int wglob = blockIdx.x * 4 + wv;
  int row = lane & 15, kq = lane >> 4;
  for (int it = 0; it < 4; it++) {
    int tile = wglob * 4 + it;
    size_t p0 = (size_t)tile * 16;
    const float* Ab = pfea + (p0 + row) * 256 + kq * 8;
    f32x4 acc = {0.f, 0.f, 0.f, 0.f};
    #pragma unroll
    for (int ks = 0; ks < 8; ks++) {
      float4 f0 = *(const float4*)(Ab + ks * 32);
      float4 f1 = *(const float4*)(Ab + ks * 32 + 4);
      short8 af;
      af[0] = (short)rne_bf16(f0.x); af[1] = (short)rne_bf16(f0.y);
      af[2] = (short)rne_bf16(f0.z); af[3] = (short)rne_bf16(f0.w);
      af[4] = (short)rne_bf16(f1.x); af[5] = (short)rne_bf16(f1.y);
      af[6] = (short)rne_bf16(f1.z); af[7] = (short)rne_bf16(f1.w);
      short8 bfv = *(const short8*)(&wbf[ks][lane][0]);
      acc = __builtin_amdgcn_mfma_f32_16x16x32_bf16(af, bfv, acc, 0, 0, 0);
    }
    int col = lane & 15;
    if (col < 12) {
      #pragma unroll
      for (int r = 0; r < 4; r++) {
        size_t pr = p0 + kq * 4 + r;
        bmat[pr * 12 + col] = acc[r];
      }
    }
  }
}

// ---------------- logit (qk/4 - coef*d2) ----------------
__device__ __forceinline__ float lt1_val(
    const float* __restrict__ proj, const float* __restrict__ kpg,
    const float* qs_, const float* qps_, float coef, int jg, int h) {
  const float4* kr = (const float4*)(proj + (size_t)jg*1152 + 192 + h*16);
  const float4* qr = (const float4*)(qs_ + h*16);
  float qk = 0.f;
  #pragma unroll
  for (int m = 0; m < 4; m++) {
    float4 kv = kr[m], qv = qr[m];
    qk += qv.x*kv.x + qv.y*kv.y + qv.z*kv.z + qv.w*kv.w;
  }
  const float4* kpr = (const float4*)(kpg + (size_t)jg*144 + h*12);
  const float4* qpr = (const float4*)(qps_ + h*12);
  float d2 = 0.f;
  #pragma unroll
  for (int m = 0; m < 3; m++) {
    float4 kv = kpr[m], qv = qpr[m];
    float dx = qv.x-kv.x, dy = qv.y-kv.y, dz = qv.z-kv.z, dw = qv.w-kv.w;
    d2 += dx*dx + dy*dy + dz*dz + dw*dw;
  }
  return qk*0.25f - coef*d2;
}

// ---------------- fused attention: Lw precomputed in LDS, stream pfea once ---
// 768 thr = 12 waves. Prologue: Lw[j][h] = exp(WL*(lt1 + bmat)) into LDS
// (8 items/thread). Hot loop per row: pfea float4 (2-deep prefetch) +
// broadcast LDS wv + coalesced v/vp floats + 56 FMA. No cross-lane ops.
__global__ __launch_bounds__(768) void attn5_kernel(
    const float* __restrict__ proj, const float* __restrict__ qpg,
    const float* __restrict__ kpg, const float* __restrict__ vpg,
    const float* __restrict__ pfea, const float* __restrict__ bmat,
    const float* __restrict__ rotb, const float* __restrict__ trsl,
    const float* __restrict__ scale, float* __restrict__ shid) {
  __shared__ float Lws[512][12];                     // 24576 B
  __shared__ __align__(16) float4 opred[12][2][64];  // 24576 B
  __shared__ __align__(16) float qs[12][16];
  __shared__ __align__(16) float qps[12][12];
  __shared__ float coefs[12], sh_inv[12], rot_s[9];
  __shared__ float ovpg_l[12][24];

  int i = blockIdx.x, t = threadIdx.x;
  int w = t >> 6, lane = t & 63;

  for (int idx = t; idx < 192; idx += 768) qs[idx >> 4][idx & 15] = proj[i*1152 + idx];
  for (int idx = t; idx < 144; idx += 768) qps[idx / 12][idx % 12] = qpg[i*144 + idx];
  if (t < 12) coefs[t] = WC_CONST * 0.5f * log1pf(__expf(scale[t]));
  if (t < 9)  rot_s[t] = rotb[i*9 + t];
  __syncthreads();

  // Lw fill: 512*12 / 768 = 8 per thread (bmat read coalesced)
  #pragma unroll
  for (int r = 0; r < 8; r++) {
    int idx = t + r * 768;
    int j = idx / 12, h = idx - j * 12;
    float lb = lt1_val(proj, kpg, &qs[0][0], &qps[0][0], coefs[h], j, h);
    Lws[j][h] = __expf(WL_CONST * (lb + bmat[(size_t)i * 6144 + idx]));
  }
  __syncthreads();

  // sh_inv[w] per wave (once per block)
  {
    float sacc = 0.f;
    #pragma unroll
    for (int r2 = 0; r2 < 8; r2++) sacc += Lws[lane + 64 * r2][w];
    #pragma unroll
    for (int off = 32; off >= 1; off >>= 1) sacc += __shfl_xor(sacc, off);
    if (lane == 0) sh_inv[w] = 1.0f / sacc;
  }

  // accumulators
  float4 opacc[12];
  #pragma unroll
  for (int h = 0; h < 12; h++) { opacc[h].x=0.f; opacc[h].y=0.f; opacc[h].z=0.f; opacc[h].w=0.f; }
  float accv[3] = {0.f, 0.f, 0.f};
  float accvp[5] = {0.f, 0.f, 0.f, 0.f, 0.f};
  int hv0 = lane >> 4, hv1 = 4 + (lane >> 4), hv2 = 8 + (lane >> 4);
  int hp0 = lane / 24, hp1 = (lane + 64) / 24, hp2 = (lane + 128) / 24,
      hp3 = (lane + 192) / 24, hp4 = (lane + 256) / 24;

  const float* pf = pfea + (size_t)i * 131072 + (lane << 2);
  int nrows = (w < 8) ? 43 : 42;   // 512 = 8*43 + 4*42

  float4 pv0 = *(const float4*)(pf + (size_t)w * 256);
  float4 pv1 = *(const float4*)(pf + (size_t)(w + 12) * 256);

  for (int r = 0; r < nrows; r++) {
    int j = w + 12 * r;
    float4 pv = pv0;
    pv0 = pv1;
    int jn = w + 12 * (r + 2); if (jn > 511) jn = 511;
    pv1 = *(const float4*)(pf + (size_t)jn * 256);

    const float* vrow  = proj + (size_t)j * 1152 + 384 + lane;
    const float* vprow = vpg  + (size_t)j * 288 + lane;
    float vv0 = vrow[0],  vv1 = vrow[64],  vv2 = vrow[128];
    float vp0 = vprow[0], vp1 = vprow[64], vp2 = vprow[128], vp3 = vprow[192];
    float vp4 = (lane < 32) ? vprow[256] : 0.f;

    const float4* lwp = (const float4*)&Lws[j][0];
    float4 lw0 = lwp[0], lw1 = lwp[1], lw2 = lwp[2];
    float wv[12] = {lw0.x, lw0.y, lw0.z, lw0.w,
                    lw1.x, lw1.y, lw1.z, lw1.w,
                    lw2.x, lw2.y, lw2.z, lw2.w};
    #pragma unroll
    for (int h = 0; h < 12; h++) {
      opacc[h].x += wv[h] * pv.x; opacc[h].y += wv[h] * pv.y;
      opacc[h].z += wv[h] * pv.z; opacc[h].w += wv[h] * pv.w;
    }
    accv[0] += wv[hv0] * vv0; accv[1] += wv[hv1] * vv1; accv[2] += wv[hv2] * vv2;
    accvp[0] += wv[hp0] * vp0; accvp[1] += wv[hp1] * vp1;
    accvp[2] += wv[hp2] * vp2; accvp[3] += wv[hp3] * vp3;
    if (lane < 32) accvp[4] += wv[hp4] * vp4;
  }
  __syncthreads();

  // ---- op reduce: 6 rounds of 2 heads ----
  #pragma unroll
  for (int g = 0; g < 6; g++) {
    opred[w][0][lane] = opacc[2*g + 0];
    opred[w][1][lane] = opacc[2*g + 1];
    __syncthreads();
    if (t < 128) {
      int hh = t >> 6, ll = t & 63;
      float4 s = {0.f, 0.f, 0.f, 0.f};
      #pragma unroll
      for (int w2 = 0; w2 < 12; w2++) {
        float4 v = opred[w2][hh][ll];
        s.x += v.x; s.y += v.y; s.z += v.z; s.w += v.w;
      }
      int h = 2*g + hh;
      float isv = sh_inv[h];
      float4 o = {s.x*isv, s.y*isv, s.z*isv, s.w*isv};
      *(float4*)(shid + (size_t)i * 3648 + h * 304 + (ll << 2)) = o;
    }
    __syncthreads();
  }

  // ---- ov reduce ----
  float* fred = (float*)&opred[0][0][0];
  fred[w * 192 + lane]       = accv[0];
  fred[w * 192 + 64 + lane]  = accv[1];
  fred[w * 192 + 128 + lane] = accv[2];
  __syncthreads();
  if (t < 192) {
    int h = t >> 4;
    float s = 0.f;
    #pragma unroll
    for (int w2 = 0; w2 < 12; w2++) s += fred[w2 * 192 + t];
    shid[(size_t)i * 3648 + h * 304 + 256 + (t & 15)] = s * sh_inv[h];
  }
  __syncthreads();

  // ---- ovp reduce ----
  #pragma unroll
  for (int k = 0; k < 4; k++) fred[w * 288 + 64 * k + lane] = accvp[k];
  if (lane < 32) fred[w * 288 + 256 + lane] = accvp[4];
  __syncthreads();
  if (t < 288) {
    int h = t / 24;
    float s = 0.f;
    #pragma unroll
    for (int w2 = 0; w2 < 12; w2++) s += fred[w2 * 288 + t];
    ovpg_l[h][t - h * 24] = s * sh_inv[h];
  }
  __syncthreads();

  // ---- ovp = rot^T (ovp_g - t), norms ----
  if (t < 96) {
    int h = t >> 3, vv = t & 7;
    float x = ovpg_l[h][vv*3+0] - trsl[i*3+0];
    float y = ovpg_l[h][vv*3+1] - trsl[i*3+1];
    float z = ovpg_l[h][vv*3+2] - trsl[i*3+2];
    float o0 = rot_s[0]*x + rot_s[3]*y + rot_s[6]*z;
    float o1 = rot_s[1]*x + rot_s[4]*y + rot_s[7]*z;
    float o2 = rot_s[2]*x + rot_s[5]*y + rot_s[8]*z;
    float* so = shid + (size_t)i*3648 + h*304 + 272 + vv*3;
    so[0] = o0; so[1] = o1; so[2] = o2;
    shid[(size_t)i*3648 + h*304 + 296 + vv] = sqrtf(o0*o0 + o1*o1 + o2*o2);
  }
}

// ---------------- LayerNorm over 384 ----------------
__global__ __launch_bounds__(384) void ln384_kernel(
    const float* __restrict__ resid, const float* __restrict__ C, const float* __restrict__ bias,
    const float* __restrict__ g, const float* __restrict__ be, float* __restrict__ out) {
  int i = blockIdx.x, t = threadIdx.x;
  __shared__ float red[6];
  float x = resid[(size_t)i*384 + t] + C[(size_t)i*384 + t] + bias[t];
  float s = x;
  #pragma unroll
  for (int off = 32; off >= 1; off >>= 1) s += __shfl_xor(s, off);
  if ((t & 63) == 0) red[t >> 6] = s;
  __syncthreads();
  float m = (red[0]+red[1]+red[2]+red[3]+red[4]+red[5]) * (1.f/384.f);
  __syncthreads();
  float d = x - m;
  float v = d * d;
  #pragma unroll
  for (int off = 32; off >= 1; off >>= 1) v += __shfl_xor(v, off);
  if ((t & 63) == 0) red[t >> 6] = v;
  __syncthreads();
  float var = (red[0]+red[1]+red[2]+red[3]+red[4]+red[5]) * (1.f/384.f);
  out[(size_t)i*384 + t] = d * rsqrtf(var + 1e-5f) * g[t] + be[t];
}

// ---------------- launcher ----------------
extern "C" void kernel_launch(void* const* d_in, const int* in_sizes, int n_in,
                              void* d_out, int out_size, void* d_ws, size_t ws_size,
                              hipStream_t stream) {
  const float* sfea = (const float*)d_in[0];
  const float* pfea = (const float*)d_in[1];
  const float* quat = (const float*)d_in[2];
  const float* trsl = (const float*)d_in[3];
  const float* Wq   = (const float*)d_in[4];
  const float* Wk   = (const float*)d_in[5];
  const float* Wv   = (const float*)d_in[6];
  const float* Wqp  = (const float*)d_in[7];
  const float* Wkp  = (const float*)d_in[8];
  const float* Wvp  = (const float*)d_in[9];
  const float* Wb   = (const float*)d_in[10];
  const float* scale= (const float*)d_in[11];
  const float* Wsm  = (const float*)d_in[12];
  const float* bs   = (const float*)d_in[13];
  const float* W1   = (const float*)d_in[14];
  const float* b1   = (const float*)d_in[15];
  const float* W2   = (const float*)d_in[16];
  const float* b2   = (const float*)d_in[17];
  const float* W3   = (const float*)d_in[18];
  const float* b3   = (const float*)d_in[19];
  const float* g1   = (const float*)d_in[20];
  const float* be1  = (const float*)d_in[21];
  const float* g2   = (const float*)d_in[22];
  const float* be2  = (const float*)d_in[23];
  float* out = (float*)d_out;
  float* wsf = (float*)d_ws;

  float* Wcat = wsf;                     // 442368
  float* proj = Wcat + 442368;           // 589824
  float* rotb = proj + 589824;           // 4608
  float* qpg  = rotb + 4608;             // 73728
  float* kpg  = qpg + 73728;             // 73728
  float* vpg  = kpg + 73728;             // 147456
  float* bmat = vpg + 147456;            // 3145728
  float* shid = bmat + 3145728;          // 1867776
  float* cpart= shid + 1867776;          // 1179648
  float* C1   = cpart + 1179648;         // 196608
  float* s1   = C1 + 196608;             // 196608
  float* h1   = s1 + 196608;             // 196608
  float* h2   = h1 + 196608;             // 196608
  float* C3   = h2 + 196608;             // 196608

  concat_w_kernel<<<1728, 256, 0, stream>>>(Wq, Wk, Wv, Wqp, Wkp, Wvp, Wcat);
  gemm64_kernel<<<dim3(18, 8, 1), 256, 0, stream>>>(sfea, Wcat, proj, 512, 1152, 384, 384);
  frames_kernel<<<512, 64, 0, stream>>>(proj, quat, trsl, rotb, qpg, kpg, vpg);
  bgemm_kernel<<<1024, 256, 0, stream>>>(pfea, Wb, bmat);
  attn5_kernel<<<512, 768, 0, stream>>>(proj, qpg, kpg, vpg, pfea, bmat, rotb, trsl, scale, shid);

  gemm64_kernel<<<dim3(6, 8, 6), 256, 0, stream>>>(shid, Wsm, cpart, 512, 384, 3648, 608);
  reduce_kernel<<<768, 256, 0, stream>>>(cpart, C1, nullptr, 0, 196608, 384, 6);
  ln384_kernel<<<512, 384, 0, stream>>>(sfea, C1, bs, g1, be1, s1);

  gemm32_kernel<<<dim3(12, 16), 256, 0, stream>>>(s1, W1, b1, h1, 512, 384, 384, 1);
  gemm32_kernel<<<dim3(12, 16), 256, 0, stream>>>(h1, W2, b2, h2, 512, 384, 384, 1);
  gemm32_kernel<<<dim3(12, 16), 256, 0, stream>>>(h2, W3, nullptr, C3, 512, 384, 384, 0);
  ln384_kernel<<<512, 384, 0, stream>>>(s1, C3, b3, g2, be2, out);
}